// Round 5
// baseline (15008.057 us; speedup 1.0000x reference)
//
#include <hip/hip_runtime.h>
#include <stdint.h>

typedef unsigned int uint;

#define T_SEQ 512
#define D_IN 64
#define H_ 256
#define KTOT 320      // D_IN + H_
#define NTOT 1024     // 4*H_
#define MID_ 64
#define ACT_ 3
#define B_TOT 1024
#define ROWS 16       // batch rows per block
#define NBLK 64
#define THREADS 1024  // 16 waves, 4 waves/SIMD
#define KB 10         // K blocks of 32 (320/32)
#define APAD 328      // padded A-row stride (elements)
#define WP_ELEMS 40960                  // uint4 per weight plane (64 nt * 10 kb * 64)
#define WP_BYTES (WP_ELEMS * 16)        // 640 KB per plane
#define WP0_OFF 1024
#define WP1_OFF (WP0_OFF + WP_BYTES)
#define INV4096 2.44140625e-4f          // 2^-12

typedef _Float16 half_t;
typedef __attribute__((ext_vector_type(8))) _Float16 half8;
typedef __attribute__((ext_vector_type(4))) float floatx4;

__device__ inline float bf2f(unsigned short s) {
  union { uint u; float f; } v; v.u = ((uint)s) << 16; return v.f;
}
union UHU { half_t h; unsigned short u; };
__device__ inline unsigned short h2u(half_t h) { UHU v; v.h = h; return v.u; }
union U4H8 { uint4 u; half8 h; };
__device__ inline half8 u4h8(uint4 v) { U4H8 t; t.u = v; return t.h; }

// load input element idx as float, from fp32 or bf16 storage
__device__ inline float ldin(const void* p, int idx, int isf) {
  return isf ? ((const float*)p)[idx] : bf2f(((const unsigned short*)p)[idx]);
}

// 2-digit fp16 split with scaled residual: f ≈ d0 + d1*2^-12, rel err ~2^-22.
__device__ inline void split2h(float f, half_t& d0, half_t& d1) {
  d0 = (half_t)f;                       // RNE
  float r = f - (float)d0;              // exact in fp32
  d1 = (half_t)(r * 4096.0f);           // exact scale; RNE round
}

// force a wave-uniform pointer into SGPRs (saves VGPR pairs per W stream)
__device__ inline const uint4* uni(const uint4* p) {
  uint64_t v = (uint64_t)p;
  uint lo = __builtin_amdgcn_readfirstlane((uint)v);
  uint hi = __builtin_amdgcn_readfirstlane((uint)(v >> 32));
  return (const uint4*)(((uint64_t)hi << 32) | lo);
}

// ---- dtype detector: fp32 storage => low halves of floats are mantissa junk
__global__ void detect_dtype(const unsigned short* __restrict__ x,
                             int* __restrict__ flag) {
  if (blockIdx.x == 0 && threadIdx.x == 0) {
    int f = 0;
    for (int i = 0; i < 256; ++i) {
      float v = bf2f(x[i]);
      if (!(fabsf(v) < 1e10f)) f = 1;   // catches huge, inf, NaN
    }
    *flag = f;
  }
}

// Repack Wc (KTOT x NTOT, row-major) into 2 fp16-digit MFMA B-fragment planes:
// frag index = nt*KB + kb ; element = frag*64 + lane ; lane holds
// B[k = kb*32 + (lane>>4)*8 + j][n = nt*16 + (lane&15)], j=0..7 packed in 16B.
__global__ void repack_wc(const void* __restrict__ Wc,
                          uint4* __restrict__ W0, uint4* __restrict__ W1,
                          const int* __restrict__ flag) {
  int tid = blockIdx.x * blockDim.x + threadIdx.x;  // 40960 threads
  int lane = tid & 63;
  int frag = tid >> 6;                              // 0..639
  int nt = frag / KB;
  int kb = frag - nt * KB;
  int n = nt * 16 + (lane & 15);
  int k0 = kb * 32 + (lane >> 4) * 8;
  int isf = *flag;
  unsigned short e0[8], e1[8];
#pragma unroll
  for (int j = 0; j < 8; ++j) {
    size_t idx = (size_t)(k0 + j) * NTOT + n;
    float w = isf ? ((const float*)Wc)[idx] : bf2f(((const unsigned short*)Wc)[idx]);
    half_t d0, d1;
    split2h(w, d0, d1);
    e0[j] = h2u(d0);
    e1[j] = h2u(d1);
  }
  uint4 o0, o1;
  o0.x = (uint)e0[0] | ((uint)e0[1] << 16);
  o0.y = (uint)e0[2] | ((uint)e0[3] << 16);
  o0.z = (uint)e0[4] | ((uint)e0[5] << 16);
  o0.w = (uint)e0[6] | ((uint)e0[7] << 16);
  o1.x = (uint)e1[0] | ((uint)e1[1] << 16);
  o1.y = (uint)e1[2] | ((uint)e1[3] << 16);
  o1.z = (uint)e1[4] | ((uint)e1[5] << 16);
  o1.w = (uint)e1[6] | ((uint)e1[7] << 16);
  W0[tid] = o0;
  W1[tid] = o1;
}

// LDS is padded past 80 KB so at most ONE block fits per CU: the backend's
// occupancy analysis then budgets 128 VGPRs (4 waves/EU) instead of the 64 it
// chose when 2 blocks/CU looked feasible (rounds 2-3: VGPR_Count=64, prefetch
// pipeline collapsed, all pipes <4% busy).
__global__ __launch_bounds__(THREADS, 4)
__attribute__((amdgpu_waves_per_eu(4, 4))) void xlstm_main(
    const void* __restrict__ xg,
    const void* __restrict__ bc,
    const uint4* __restrict__ W0, const uint4* __restrict__ W1,
    const void* __restrict__ Wa1, const void* __restrict__ ba1,
    const void* __restrict__ Wa2, const void* __restrict__ ba2,
    const void* __restrict__ Wv1, const void* __restrict__ bv1,
    const void* __restrict__ Wv2, const void* __restrict__ bv2,
    void* __restrict__ outv,
    const int* __restrict__ flagp)
{
  __shared__ unsigned short A0[2][ROWS][APAD];   // digit-0 plane [xt | h], dbuf
  __shared__ unsigned short A1[2][ROWS][APAD];   // digit-1 plane (scaled 2^12)
  __shared__ float h32[ROWS][H_ + 4];            // final h in fp32 for the heads
  __shared__ float mida[ROWS][MID_ + 2];
  __shared__ float midv[ROWS][MID_ + 2];
  __shared__ float lgts[ROWS][4];
  __shared__ char occ_pad[16384];                // occupancy limiter (see above)

  const int tid = threadIdx.x;
  const int lane = tid & 63;
  const int wave = tid >> 6;                     // 0..15
  const int b0 = blockIdx.x * ROWS;
  const int isf = *flagp;                        // uniform
  if (isf > 1) occ_pad[tid] = 1;                 // never true; keeps pad alive

  // zero h-section of both planes of buffer 0 (h0 = 0): 4 shorts per thread
  {
    int r = tid >> 6;                            // 0..15
    int c0 = 64 + (tid & 63) * 4;                // 64..316
    *(uint2*)&A0[0][r][c0] = make_uint2(0u, 0u);
    *(uint2*)&A1[0][r][c0] = make_uint2(0u, 0u);
  }

  // x staging: each thread owns exactly 1 x element of one row per step
  const int xr = tid >> 6;                       // row 0..15
  const int xcol = tid & 63;                     // col 0..63
  const unsigned short* xu_base =
      (const unsigned short*)xg + ((size_t)(b0 + xr) * T_SEQ) * 64 + xcol;
  const float* xf_base =
      (const float*)xg + ((size_t)(b0 + xr) * T_SEQ) * 64 + xcol;
  unsigned short x0, x1;
  {
    float a = isf ? xf_base[0] : bf2f(xu_base[0]);
    half_t d0, d1;
    split2h(a, d0, d1);
    x0 = h2u(d0); x1 = h2u(d1);
  }

  const int l15 = lane & 15;
  const int quad = lane >> 4;
  const int crow = quad * 4;                     // C-layout row base
  const int u = wave * 16 + l15;                 // hidden unit owned by this lane

  const float bi  = ldin(bc, u, isf);
  const float bfg = ldin(bc, H_ + u, isf);
  const float bo  = ldin(bc, 2 * H_ + u, isf);
  const float bz  = ldin(bc, 3 * H_ + u, isf);

  // W stream bases (wave-uniform, in SGPRs). Wave owns tiles nt = g*16 + wave.
  const uint4* bp0[4];
  const uint4* bp1[4];
#pragma unroll
  for (int g = 0; g < 4; ++g) {
    const size_t toff = (size_t)((g * 16 + wave) * KB) * 64;
    bp0[g] = uni(W0 + toff);
    bp1[g] = uni(W1 + toff);
  }

  float cst[4], nst[4];
#pragma unroll
  for (int r = 0; r < 4; ++r) { cst[r] = 0.f; nst[r] = 1.f; }

  // preload kb=0 fragments of both planes (per-lane offset lane*16 bytes)
  uint koff = (uint)lane * 16u;
  uint4 wa[4], wb[4];
#pragma unroll
  for (int g = 0; g < 4; ++g) wa[g] = *(const uint4*)((const char*)bp0[g] + koff);
#pragma unroll
  for (int g = 0; g < 4; ++g) wb[g] = *(const uint4*)((const char*)bp1[g] + koff);

  for (int t = 0; t < T_SEQ; ++t) {
    const int cur = t & 1, nxt = cur ^ 1;
    A0[cur][xr][xcol] = x0;                      // write x(t) digits
    A1[cur][xr][xcol] = x1;
    // LDS-only barrier: drain lgkm (my ds writes visible), DO NOT drain vmcnt
    // so W prefetch loads stay in flight across the step boundary.
    asm volatile("s_waitcnt lgkmcnt(0)\n\ts_barrier" ::: "memory");

    // issue the x(t+1) load NOW, but defer its split2h until AFTER the GEMM:
    // splitting here would force an early vmcnt wait for x (HBM-latency) that
    // also drains the in-flight W prefetch every step.
    float xa_f = 0.f; uint xa_u = 0;
    if (t + 1 < T_SEQ) {
      if (isf) xa_f = xf_base[(size_t)(t + 1) * 64];
      else     xa_u = (uint)xu_base[(size_t)(t + 1) * 64];
    }

    // gates GEMM, 2-digit fp16 split with scaled-residual planes:
    //   gate = (a0·w0) + 2^-12 · (a0·w1' + a1'·w0)     [a1'w1' ~2^-24, dropped]
    // Per-accumulator order identical to the verified kernel:
    //   accA: fa0*w0 kb-ascending; accB: per kb fa1*w0 then fa0*w1.
    // sched_barrier(0) fences pin the depth-1 pipeline: {ds_read + next-kb W
    // issue} | {12 MFMAs on current kb} — the scheduler cannot sink the
    // prefetch loads to their use point anymore.
    floatx4 accA[4], accB[4];
#pragma unroll
    for (int g = 0; g < 4; ++g) {
      accA[g] = (floatx4){0.f, 0.f, 0.f, 0.f};
      accB[g] = (floatx4){0.f, 0.f, 0.f, 0.f};
    }
#pragma unroll
    for (int kb = 0; kb < KB; ++kb) {
      const half8 fa0 = u4h8(*(const uint4*)&A0[cur][l15][kb * 32 + quad * 8]);
      const half8 fa1 = u4h8(*(const uint4*)&A1[cur][l15][kb * 32 + quad * 8]);
      // prefetch kb+1 (or kb=0 for the NEXT timestep when kb==9, so the load
      // latency hides under the sLSTM update + barrier)
      const uint koff2 = (kb < KB - 1) ? (koff + 1024u) : ((uint)lane * 16u);
      uint4 na[4], nb[4];
#pragma unroll
      for (int g = 0; g < 4; ++g)
        na[g] = *(const uint4*)((const char*)bp0[g] + koff2);
#pragma unroll
      for (int g = 0; g < 4; ++g)
        nb[g] = *(const uint4*)((const char*)bp1[g] + koff2);
      __builtin_amdgcn_sched_barrier(0);
      // consume current kb
#pragma unroll
      for (int g = 0; g < 4; ++g)
        accA[g] = __builtin_amdgcn_mfma_f32_16x16x32_f16(fa0, u4h8(wa[g]),
                                                         accA[g], 0, 0, 0);
#pragma unroll
      for (int g = 0; g < 4; ++g)
        accB[g] = __builtin_amdgcn_mfma_f32_16x16x32_f16(fa1, u4h8(wa[g]),
                                                         accB[g], 0, 0, 0);
#pragma unroll
      for (int g = 0; g < 4; ++g)
        accB[g] = __builtin_amdgcn_mfma_f32_16x16x32_f16(fa0, u4h8(wb[g]),
                                                         accB[g], 0, 0, 0);
      __builtin_amdgcn_sched_barrier(0);
      // rotate prefetch buffers (SSA renames under full unroll, no real movs)
#pragma unroll
      for (int g = 0; g < 4; ++g) { wa[g] = na[g]; wb[g] = nb[g]; }
      koff = koff2;
    }

    // now split the prefetched x(t+1) — its load latency hid under the GEMM
    if (t + 1 < T_SEQ) {
      float a = isf ? xa_f : bf2f((unsigned short)xa_u);
      half_t d0, d1;
      split2h(a, d0, d1);
      x0 = h2u(d0); x1 = h2u(d1);
    }

    // sLSTM update, all in registers (lane owns 4 (row,unit) pairs)
#pragma unroll
    for (int r = 0; r < 4; ++r) {
      float gi = accA[0][r] + accB[0][r] * INV4096 + bi;
      float gf = accA[1][r] + accB[1][r] * INV4096 + bfg;
      float ov = accA[2][r] + accB[2][r] * INV4096 + bo;
      float zv = accA[3][r] + accB[3][r] * INV4096 + bz;
      float iv = __expf(fminf(fmaxf(gi, -5.f), 5.f));
      float fv = __expf(fminf(fmaxf(gf, -5.f), 5.f));
      float e2z = __expf(2.f * zv);
      float tz = 1.f - 2.f / (e2z + 1.f);        // tanh, exact div
      float cv = fv * cst[r] + iv * tz;
      cv = fminf(fmaxf(cv, -1e6f), 1e6f);
      float nv = fv * nst[r] + iv;
      nv = fminf(fmaxf(nv, 1e-6f), 1e6f);
      cst[r] = cv; nst[r] = nv;
      float sg = 1.f / (1.f + __expf(-ov));      // sigmoid, exact div
      float hv = sg * (cv / nv);
      if (!(fabsf(hv) < 1e37f)) hv = 0.f;        // nan_to_num(nan/±inf -> 0)
      half_t d0, d1;
      split2h(hv, d0, d1);
      A0[nxt][crow + r][64 + u] = h2u(d0);
      A1[nxt][crow + r][64 + u] = h2u(d1);
      if (t == T_SEQ - 1) h32[crow + r][u] = hv;
    }
  }
  __syncthreads();                               // full drain before heads

  // ---- heads (fp32 VALU, one-time) ----
  {
    int r = tid >> 6, m = tid & 63;              // 1024 threads = 16 rows x 64
    float sa = ldin(ba1, m, isf);
    float sv = ldin(bv1, m, isf);
    for (int k = 0; k < H_; ++k) {
      float hv = h32[r][k];
      sa += hv * ldin(Wa1, k * MID_ + m, isf);
      sv += hv * ldin(Wv1, k * MID_ + m, isf);
    }
    mida[r][m] = fmaxf(sa, 0.f);
    midv[r][m] = fmaxf(sv, 0.f);
  }
  __syncthreads();
  if (tid < ROWS * 4) {
    int r = tid >> 2, j = tid & 3;
    if (j < 3) {
      float s = ldin(ba2, j, isf);
      for (int m = 0; m < MID_; ++m) s += mida[r][m] * ldin(Wa2, m * ACT_ + j, isf);
      lgts[r][j] = s;
    } else {
      float s = ldin(bv2, 0, isf);
      for (int m = 0; m < MID_; ++m) s += midv[r][m] * ldin(Wv2, m, isf);
      int oi = 3 * B_TOT + b0 + r;               // value output
      if (isf) ((float*)outv)[oi] = s; else ((unsigned short*)outv)[oi] = 0;
    }
  }
  __syncthreads();
  if (tid < ROWS) {
    float l0 = lgts[tid][0], l1 = lgts[tid][1], l2 = lgts[tid][2];
    float mx = fmaxf(l0, fmaxf(l1, l2));
    float e0 = __expf(l0 - mx), e1 = __expf(l1 - mx), e2 = __expf(l2 - mx);
    float inv = 1.f / (e0 + e1 + e2);
    int oi = (b0 + tid) * 3;
    ((float*)outv)[oi + 0] = e0 * inv;
    ((float*)outv)[oi + 1] = e1 * inv;
    ((float*)outv)[oi + 2] = e2 * inv;
  }
}

extern "C" void kernel_launch(void* const* d_in, const int* in_sizes, int n_in,
                              void* d_out, int out_size, void* d_ws, size_t ws_size,
                              hipStream_t stream) {
  const void* x   = d_in[0];
  const void* Wc  = d_in[1];
  const void* bc  = d_in[2];
  const void* Wa1 = d_in[3];
  const void* ba1 = d_in[4];
  const void* Wa2 = d_in[5];
  const void* ba2 = d_in[6];
  const void* Wv1 = d_in[7];
  const void* bv1 = d_in[8];
  const void* Wv2 = d_in[9];
  const void* bv2 = d_in[10];

  int*   flag = (int*)d_ws;
  uint4* W0p  = (uint4*)((char*)d_ws + WP0_OFF);   // 640 KB digit-0 plane
  uint4* W1p  = (uint4*)((char*)d_ws + WP1_OFF);   // 640 KB scaled digit-1 plane

  detect_dtype<<<1, 64, 0, stream>>>((const unsigned short*)x, flag);
  repack_wc<<<160, 256, 0, stream>>>(Wc, W0p, W1p, flag);
  xlstm_main<<<NBLK, THREADS, 0, stream>>>(x, bc, W0p, W1p,
                                           Wa1, ba1, Wa2, ba2,
                                           Wv1, bv1, Wv2, bv2, d_out, flag);
}

// Round 6
// 11011.179 us; speedup vs baseline: 1.3630x; 1.3630x over previous
//
#include <hip/hip_runtime.h>
#include <stdint.h>

typedef unsigned int uint;

#define T_SEQ 512
#define D_IN 64
#define H_ 256
#define KTOT 320      // D_IN + H_
#define NTOT 1024     // 4*H_
#define MID_ 64
#define ACT_ 3
#define B_TOT 1024
#define ROWS 16       // batch rows per block
#define NBLK 64
#define THREADS 1024  // 16 waves, 4 waves/SIMD
#define KB 10         // K blocks of 32 (320/32)
#define APAD 328      // padded A-row stride (elements)
#define WP_ELEMS 40960                  // uint4 per weight plane (64 nt * 10 kb * 64)
#define WP_BYTES (WP_ELEMS * 16)        // 640 KB per plane
#define WP0_OFF 1024
#define WP1_OFF (WP0_OFF + WP_BYTES)
#define INV4096 2.44140625e-4f          // 2^-12

typedef _Float16 half_t;
typedef __attribute__((ext_vector_type(8))) _Float16 half8;
typedef __attribute__((ext_vector_type(4))) float floatx4;

__device__ inline float bf2f(unsigned short s) {
  union { uint u; float f; } v; v.u = ((uint)s) << 16; return v.f;
}
union UHU { half_t h; unsigned short u; };
__device__ inline unsigned short h2u(half_t h) { UHU v; v.h = h; return v.u; }
union U4H8 { uint4 u; half8 h; };
__device__ inline half8 u4h8(uint4 v) { U4H8 t; t.u = v; return t.h; }

// load input element idx as float, from fp32 or bf16 storage
__device__ inline float ldin(const void* p, int idx, int isf) {
  return isf ? ((const float*)p)[idx] : bf2f(((const unsigned short*)p)[idx]);
}

// 2-digit fp16 split with scaled residual: f ≈ d0 + d1*2^-12, rel err ~2^-22.
__device__ inline void split2h(float f, half_t& d0, half_t& d1) {
  d0 = (half_t)f;                       // RNE
  float r = f - (float)d0;              // exact in fp32
  d1 = (half_t)(r * 4096.0f);           // exact scale; RNE round
}

// force a wave-uniform pointer into SGPRs (saves VGPR pairs per W stream)
__device__ inline const uint4* uni(const uint4* p) {
  uint64_t v = (uint64_t)p;
  uint lo = __builtin_amdgcn_readfirstlane((uint)v);
  uint hi = __builtin_amdgcn_readfirstlane((uint)(v >> 32));
  return (const uint4*)(((uint64_t)hi << 32) | lo);
}

// ---- dtype detector: fp32 storage => low halves of floats are mantissa junk
__global__ void detect_dtype(const unsigned short* __restrict__ x,
                             int* __restrict__ flag) {
  if (blockIdx.x == 0 && threadIdx.x == 0) {
    int f = 0;
    for (int i = 0; i < 256; ++i) {
      float v = bf2f(x[i]);
      if (!(fabsf(v) < 1e10f)) f = 1;   // catches huge, inf, NaN
    }
    *flag = f;
  }
}

// Repack Wc (KTOT x NTOT, row-major) into 2 fp16-digit MFMA B-fragment planes:
// frag index = nt*KB + kb ; element = frag*64 + lane ; lane holds
// B[k = kb*32 + (lane>>4)*8 + j][n = nt*16 + (lane&15)], j=0..7 packed in 16B.
__global__ void repack_wc(const void* __restrict__ Wc,
                          uint4* __restrict__ W0, uint4* __restrict__ W1,
                          const int* __restrict__ flag) {
  int tid = blockIdx.x * blockDim.x + threadIdx.x;  // 40960 threads
  int lane = tid & 63;
  int frag = tid >> 6;                              // 0..639
  int nt = frag / KB;
  int kb = frag - nt * KB;
  int n = nt * 16 + (lane & 15);
  int k0 = kb * 32 + (lane >> 4) * 8;
  int isf = *flag;
  unsigned short e0[8], e1[8];
#pragma unroll
  for (int j = 0; j < 8; ++j) {
    size_t idx = (size_t)(k0 + j) * NTOT + n;
    float w = isf ? ((const float*)Wc)[idx] : bf2f(((const unsigned short*)Wc)[idx]);
    half_t d0, d1;
    split2h(w, d0, d1);
    e0[j] = h2u(d0);
    e1[j] = h2u(d1);
  }
  uint4 o0, o1;
  o0.x = (uint)e0[0] | ((uint)e0[1] << 16);
  o0.y = (uint)e0[2] | ((uint)e0[3] << 16);
  o0.z = (uint)e0[4] | ((uint)e0[5] << 16);
  o0.w = (uint)e0[6] | ((uint)e0[7] << 16);
  o1.x = (uint)e1[0] | ((uint)e1[1] << 16);
  o1.y = (uint)e1[2] | ((uint)e1[3] << 16);
  o1.z = (uint)e1[4] | ((uint)e1[5] << 16);
  o1.w = (uint)e1[6] | ((uint)e1[7] << 16);
  W0[tid] = o0;
  W1[tid] = o1;
}

// LDS padded past 80 KB (via a VOLATILE store the compiler cannot DCE, unlike
// round 5's dead pad) so only ONE block fits per CU. The backend's occupancy
// analysis then plans 4 waves/EU => 128-VGPR budget, instead of the 64 it
// chose when 2 blocks/CU looked LDS-feasible (rounds 2-5: VGPR_Count=64, the
// W-prefetch pipeline collapsed / spilled). Costs nothing: 64 blocks on 256
// CUs never co-residented anyway.
__global__ __launch_bounds__(THREADS, 4) void xlstm_main(
    const void* __restrict__ xg,
    const void* __restrict__ bc,
    const uint4* __restrict__ W0, const uint4* __restrict__ W1,
    const void* __restrict__ Wa1, const void* __restrict__ ba1,
    const void* __restrict__ Wa2, const void* __restrict__ ba2,
    const void* __restrict__ Wv1, const void* __restrict__ bv1,
    const void* __restrict__ Wv2, const void* __restrict__ bv2,
    void* __restrict__ outv,
    const int* __restrict__ flagp)
{
  __shared__ unsigned short A0[2][ROWS][APAD];   // digit-0 plane [xt | h], dbuf
  __shared__ unsigned short A1[2][ROWS][APAD];   // digit-1 plane (scaled 2^12)
  __shared__ float h32[ROWS][H_ + 4];            // final h in fp32 for the heads
  __shared__ float mida[ROWS][MID_ + 2];
  __shared__ float midv[ROWS][MID_ + 2];
  __shared__ float lgts[ROWS][4];
  __shared__ uint occ_pad[4096];                 // 16 KB occupancy limiter

  const int tid = threadIdx.x;
  ((volatile uint*)occ_pad)[tid] = 0u;           // un-removable: keeps pad alive

  const int lane = tid & 63;
  const int wave = tid >> 6;                     // 0..15
  const int b0 = blockIdx.x * ROWS;
  const int isf = *flagp;                        // uniform

  // zero h-section of both planes of buffer 0 (h0 = 0): 4 shorts per thread
  {
    int r = tid >> 6;                            // 0..15
    int c0 = 64 + (tid & 63) * 4;                // 64..316
    *(uint2*)&A0[0][r][c0] = make_uint2(0u, 0u);
    *(uint2*)&A1[0][r][c0] = make_uint2(0u, 0u);
  }

  // x staging: each thread owns exactly 1 x element of one row per step
  const int xr = tid >> 6;                       // row 0..15
  const int xcol = tid & 63;                     // col 0..63
  const unsigned short* xu_base =
      (const unsigned short*)xg + ((size_t)(b0 + xr) * T_SEQ) * 64 + xcol;
  const float* xf_base =
      (const float*)xg + ((size_t)(b0 + xr) * T_SEQ) * 64 + xcol;
  unsigned short x0, x1;
  {
    float a = isf ? xf_base[0] : bf2f(xu_base[0]);
    half_t d0, d1;
    split2h(a, d0, d1);
    x0 = h2u(d0); x1 = h2u(d1);
  }

  const int l15 = lane & 15;
  const int quad = lane >> 4;
  const int crow = quad * 4;                     // C-layout row base
  const int u = wave * 16 + l15;                 // hidden unit owned by this lane

  const float bi  = ldin(bc, u, isf);
  const float bfg = ldin(bc, H_ + u, isf);
  const float bo  = ldin(bc, 2 * H_ + u, isf);
  const float bz  = ldin(bc, 3 * H_ + u, isf);

  // W stream bases (wave-uniform, in SGPRs). Wave owns tiles nt = g*16 + wave.
  const uint4* bp0[4];
  const uint4* bp1[4];
#pragma unroll
  for (int g = 0; g < 4; ++g) {
    const size_t toff = (size_t)((g * 16 + wave) * KB) * 64;
    bp0[g] = uni(W0 + toff);
    bp1[g] = uni(W1 + toff);
  }

  float cst[4], nst[4];
#pragma unroll
  for (int r = 0; r < 4; ++r) { cst[r] = 0.f; nst[r] = 1.f; }

  // preload kb=0 of the W0 plane (per-lane offset lane*16 bytes)
  uint koff = (uint)lane * 16u;
  uint4 wa[4];
#pragma unroll
  for (int g = 0; g < 4; ++g) wa[g] = *(const uint4*)((const char*)bp0[g] + koff);

  for (int t = 0; t < T_SEQ; ++t) {
    const int cur = t & 1, nxt = cur ^ 1;
    A0[cur][xr][xcol] = x0;                      // write x(t) digits
    A1[cur][xr][xcol] = x1;
    // LDS-only barrier: drain lgkm (my ds writes visible), DO NOT drain vmcnt
    // so W prefetch loads stay in flight across the step boundary.
    asm volatile("s_waitcnt lgkmcnt(0)\n\ts_barrier" ::: "memory");

    // issue the x(t+1) load NOW, but defer its split2h until AFTER the GEMM:
    // splitting here would force an early vmcnt wait for x (HBM-latency) that
    // also drains the in-flight W prefetch every step.
    float xa_f = 0.f; uint xa_u = 0;
    if (t + 1 < T_SEQ) {
      if (isf) xa_f = xf_base[(size_t)(t + 1) * 64];
      else     xa_u = (uint)xu_base[(size_t)(t + 1) * 64];
    }

    // gates GEMM, 2-digit fp16 split with scaled-residual planes:
    //   gate = (a0·w0) + 2^-12 · (a0·w1' + a1'·w0)     [a1'w1' ~2^-24, dropped]
    // Plane-alternating software pipeline (3 landing groups = 48 W-VGPRs peak,
    // fits the 128-reg budget): per kb, issue W1[kb] loads, run the 8 W0[kb]
    // MFMAs, issue W0[kb+1] loads, run the 4 W1[kb] MFMAs. No sched fences —
    // round 5 showed fences + tight budget = scratch spills; with headroom the
    // scheduler hoists these loads on its own.
    // Per-accumulator order identical to the verified kernel:
    //   accA: fa0*w0 kb-ascending; accB: per kb fa1*w0 then fa0*w1.
    floatx4 accA[4], accB[4];
#pragma unroll
    for (int g = 0; g < 4; ++g) {
      accA[g] = (floatx4){0.f, 0.f, 0.f, 0.f};
      accB[g] = (floatx4){0.f, 0.f, 0.f, 0.f};
    }
#pragma unroll
    for (int kb = 0; kb < KB; ++kb) {
      const half8 fa0 = u4h8(*(const uint4*)&A0[cur][l15][kb * 32 + quad * 8]);
      const half8 fa1 = u4h8(*(const uint4*)&A1[cur][l15][kb * 32 + quad * 8]);
      // issue W1[kb] loads; consumed 12 MFMAs below
      uint4 wb_[4];
#pragma unroll
      for (int g = 0; g < 4; ++g)
        wb_[g] = *(const uint4*)((const char*)bp1[g] + koff);
      // 8 MFMAs on W0[kb] (already in wa)
#pragma unroll
      for (int g = 0; g < 4; ++g)
        accA[g] = __builtin_amdgcn_mfma_f32_16x16x32_f16(fa0, u4h8(wa[g]),
                                                         accA[g], 0, 0, 0);
#pragma unroll
      for (int g = 0; g < 4; ++g)
        accB[g] = __builtin_amdgcn_mfma_f32_16x16x32_f16(fa1, u4h8(wa[g]),
                                                         accB[g], 0, 0, 0);
      // issue W0[kb+1] (or kb=0 of the NEXT timestep when kb==9, so its
      // latency hides under the sLSTM update + barrier)
      const uint koff2 = (kb < KB - 1) ? (koff + 1024u) : ((uint)lane * 16u);
      uint4 wa_[4];
#pragma unroll
      for (int g = 0; g < 4; ++g)
        wa_[g] = *(const uint4*)((const char*)bp0[g] + koff2);
      // 4 MFMAs on W1[kb]
#pragma unroll
      for (int g = 0; g < 4; ++g)
        accB[g] = __builtin_amdgcn_mfma_f32_16x16x32_f16(fa0, u4h8(wb_[g]),
                                                         accB[g], 0, 0, 0);
      // rotate (SSA renames under full unroll, no real movs)
#pragma unroll
      for (int g = 0; g < 4; ++g) wa[g] = wa_[g];
      koff = koff2;
    }

    // now split the prefetched x(t+1) — its load latency hid under the GEMM
    if (t + 1 < T_SEQ) {
      float a = isf ? xa_f : bf2f((unsigned short)xa_u);
      half_t d0, d1;
      split2h(a, d0, d1);
      x0 = h2u(d0); x1 = h2u(d1);
    }

    // sLSTM update, all in registers (lane owns 4 (row,unit) pairs)
#pragma unroll
    for (int r = 0; r < 4; ++r) {
      float gi = accA[0][r] + accB[0][r] * INV4096 + bi;
      float gf = accA[1][r] + accB[1][r] * INV4096 + bfg;
      float ov = accA[2][r] + accB[2][r] * INV4096 + bo;
      float zv = accA[3][r] + accB[3][r] * INV4096 + bz;
      float iv = __expf(fminf(fmaxf(gi, -5.f), 5.f));
      float fv = __expf(fminf(fmaxf(gf, -5.f), 5.f));
      float e2z = __expf(2.f * zv);
      float tz = 1.f - 2.f / (e2z + 1.f);        // tanh, exact div
      float cv = fv * cst[r] + iv * tz;
      cv = fminf(fmaxf(cv, -1e6f), 1e6f);
      float nv = fv * nst[r] + iv;
      nv = fminf(fmaxf(nv, 1e-6f), 1e6f);
      cst[r] = cv; nst[r] = nv;
      float sg = 1.f / (1.f + __expf(-ov));      // sigmoid, exact div
      float hv = sg * (cv / nv);
      if (!(fabsf(hv) < 1e37f)) hv = 0.f;        // nan_to_num(nan/±inf -> 0)
      half_t d0, d1;
      split2h(hv, d0, d1);
      A0[nxt][crow + r][64 + u] = h2u(d0);
      A1[nxt][crow + r][64 + u] = h2u(d1);
      if (t == T_SEQ - 1) h32[crow + r][u] = hv;
    }
  }
  __syncthreads();                               // full drain before heads

  // ---- heads (fp32 VALU, one-time) ----
  {
    int r = tid >> 6, m = tid & 63;              // 1024 threads = 16 rows x 64
    float sa = ldin(ba1, m, isf);
    float sv = ldin(bv1, m, isf);
    for (int k = 0; k < H_; ++k) {
      float hv = h32[r][k];
      sa += hv * ldin(Wa1, k * MID_ + m, isf);
      sv += hv * ldin(Wv1, k * MID_ + m, isf);
    }
    mida[r][m] = fmaxf(sa, 0.f);
    midv[r][m] = fmaxf(sv, 0.f);
  }
  __syncthreads();
  if (tid < ROWS * 4) {
    int r = tid >> 2, j = tid & 3;
    if (j < 3) {
      float s = ldin(ba2, j, isf);
      for (int m = 0; m < MID_; ++m) s += mida[r][m] * ldin(Wa2, m * ACT_ + j, isf);
      lgts[r][j] = s;
    } else {
      float s = ldin(bv2, 0, isf);
      for (int m = 0; m < MID_; ++m) s += midv[r][m] * ldin(Wv2, m, isf);
      int oi = 3 * B_TOT + b0 + r;               // value output
      if (isf) ((float*)outv)[oi] = s; else ((unsigned short*)outv)[oi] = 0;
    }
  }
  __syncthreads();
  if (tid < ROWS) {
    float l0 = lgts[tid][0], l1 = lgts[tid][1], l2 = lgts[tid][2];
    float mx = fmaxf(l0, fmaxf(l1, l2));
    float e0 = __expf(l0 - mx), e1 = __expf(l1 - mx), e2 = __expf(l2 - mx);
    float inv = 1.f / (e0 + e1 + e2);
    int oi = (b0 + tid) * 3;
    ((float*)outv)[oi + 0] = e0 * inv;
    ((float*)outv)[oi + 1] = e1 * inv;
    ((float*)outv)[oi + 2] = e2 * inv;
  }
}

extern "C" void kernel_launch(void* const* d_in, const int* in_sizes, int n_in,
                              void* d_out, int out_size, void* d_ws, size_t ws_size,
                              hipStream_t stream) {
  const void* x   = d_in[0];
  const void* Wc  = d_in[1];
  const void* bc  = d_in[2];
  const void* Wa1 = d_in[3];
  const void* ba1 = d_in[4];
  const void* Wa2 = d_in[5];
  const void* ba2 = d_in[6];
  const void* Wv1 = d_in[7];
  const void* bv1 = d_in[8];
  const void* Wv2 = d_in[9];
  const void* bv2 = d_in[10];

  int*   flag = (int*)d_ws;
  uint4* W0p  = (uint4*)((char*)d_ws + WP0_OFF);   // 640 KB digit-0 plane
  uint4* W1p  = (uint4*)((char*)d_ws + WP1_OFF);   // 640 KB scaled digit-1 plane

  detect_dtype<<<1, 64, 0, stream>>>((const unsigned short*)x, flag);
  repack_wc<<<160, 256, 0, stream>>>(Wc, W0p, W1p, flag);
  xlstm_main<<<NBLK, THREADS, 0, stream>>>(x, bc, W0p, W1p,
                                           Wa1, ba1, Wa2, ba2,
                                           Wv1, bv1, Wv2, bv2, d_out, flag);
}